// Round 3
// baseline (611.286 us; speedup 1.0000x reference)
//
#include <hip/hip_runtime.h>
#include <math.h>

#define Nn 512
#define Ld 64
#define NB 8
#define C1 32
#define C2 25      // 3*NB+1

// ---- exact math helpers ----
__device__ __forceinline__ float gelu_tanh(float a) {
    float a3 = a * a * a;
    float t = tanhf(0.7978845608028654f * (a + 0.044715f * a3));
    return 0.5f * a * (1.0f + t);
}

// algebraically identical to gelu_tanh: 0.5a(1+tanh(u)) == a/(1+exp(-2u))
__device__ __forceinline__ float gelu_fast(float a) {
    float a3 = a * a * a;
    float u2 = 1.5957691216057308f * (a + 0.044715f * a3);   // 2*0.79788456...
    return a / (1.0f + __expf(-u2));
}

__device__ __forceinline__ float softplus_f(float v) {
    return (v > 0.0f) ? v + log1pf(expf(-v)) : log1pf(expf(v));
}

__device__ __forceinline__ float pos_mod_2pi(float v) {
    const float T = 6.2831853071795864769f;
    float r = fmodf(v, T);
    if (r < 0.0f) r += T;
    return r;
}

// ================= K1: conv1 + gelu -> global h1 [n][row][c][col] =================
// layout: h1g[((n*64 + row)*32 + c)*64 + col]  -> per wave: 32 x 256B sequential (8KB/row)
__global__ __launch_bounds__(256, 8) void k1_conv1_kernel(
    const float* __restrict__ x,
    const float* __restrict__ c1w, const float* __restrict__ c1b,
    float* __restrict__ h1g)
{
    __shared__ float s_cos[8 * 69];
    __shared__ float s_sin[8 * 69];

    const int tid = threadIdx.x;
    const int rb  = blockIdx.x;      // 0..15 -> 4-row band
    const int n   = blockIdx.y;
    const int r0k = rb * 4;
    const float* xn = x + n * 4096;

    // stage frozen-masked cos/sin: rows r0k-2..r0k+5, cols -2..65 (wrapped)
    for (int idx = tid; idx < 8 * 68; idx += 256) {
        int li = idx / 68, lj = idx - li * 68;
        int gi = (r0k - 2 + li) & 63;
        int gj = (lj - 2) & 63;
        float xv = xn[gi * 64 + gj];
        int pat = (gi + 2 * gj) % 3;
        float sv, cv;
        sincosf(xv, &sv, &cv);
        float fz = (pat == 2) ? 1.0f : 0.0f;
        s_cos[li * 69 + lj] = fz * cv;
        s_sin[li * 69 + lj] = fz * sv;
    }
    __syncthreads();

    const int gj = tid & 63, lrow = tid >> 6;
    const int gi = r0k + lrow;

    float v[18];
    #pragma unroll
    for (int di = 0; di < 3; ++di)
        #pragma unroll
        for (int dj = 0; dj < 3; ++dj) {
            int a = (lrow + 1 + di) * 69 + (gj + 1 + dj);
            v[di * 3 + dj]     = s_cos[a];
            v[9 + di * 3 + dj] = s_sin[a];
        }

    float* outp = h1g + ((size_t)n * 64 + gi) * 2048 + gj;
    #pragma unroll 4
    for (int c = 0; c < C1; ++c) {
        const float* w = c1w + c * 18;   // uniform -> s_load
        float a1 = c1b[c];
        #pragma unroll
        for (int t = 0; t < 9; ++t) {    // cos/sin interleaved per tap (r4 order)
            a1 = fmaf(v[t],     w[t],     a1);
            a1 = fmaf(v[9 + t], w[9 + t], a1);
        }
        outp[(size_t)c * 64] = gelu_fast(a1);   // wave: 64 consecutive floats per c
    }
}

// ================= K2: conv2 + spline + passthrough + logJ =================
#define K2CH 4
#define K2PLANE 896            // 14 rows * 64 cols per staged channel plane
#define K2BUF (K2CH * K2PLANE) // 3584 floats = 14336 B single buffer

// compute one 4-channel chunk from LDS, weights base channel CBASE
#define K2_COMPUTE(CBASE)                                                 \
    {                                                                     \
        _Pragma("unroll")                                                 \
        for (int c = 0; c < K2CH; ++c) {                                  \
            const int eb = c * K2PLANE;                                   \
            float v0 = s_h1[eb + ex0];                                    \
            float v1 = s_h1[eb + ex1];                                    \
            float v2 = s_h1[eb + ex2];                                    \
            float v3 = s_h1[eb + ex0 + 64];                               \
            float v4 = s_h1[eb + ex1 + 64];                               \
            float v5 = s_h1[eb + ex2 + 64];                               \
            float v6 = s_h1[eb + ex0 + 128];                              \
            float v7 = s_h1[eb + ex1 + 128];                              \
            float v8 = s_h1[eb + ex2 + 128];                              \
            const float* wpc = c2w + ((CBASE) + c) * 9;                   \
            _Pragma("unroll")                                             \
            for (int co = 0; co < C2; ++co) {                             \
                const float* w = wpc + co * (C1 * 9);  /* uniform */      \
                float a2 = acc[co];                                       \
                a2 = fmaf(v0, w[0], a2);                                  \
                a2 = fmaf(v1, w[1], a2);                                  \
                a2 = fmaf(v2, w[2], a2);                                  \
                a2 = fmaf(v3, w[3], a2);                                  \
                a2 = fmaf(v4, w[4], a2);                                  \
                a2 = fmaf(v5, w[5], a2);                                  \
                a2 = fmaf(v6, w[6], a2);                                  \
                a2 = fmaf(v7, w[7], a2);                                  \
                a2 = fmaf(v8, w[8], a2);                                  \
                acc[co] = a2;                                             \
            }                                                             \
        }                                                                 \
    }

__global__ __launch_bounds__(256, 6) void k2_conv2_spline_kernel(
    const float* __restrict__ x, const float* __restrict__ h1g,
    const float* __restrict__ c2w, const float* __restrict__ c2b,
    float* __restrict__ out_fx, float* __restrict__ out_logJ)
{
    __shared__ float s_h1[K2BUF];   // 14336 B -> occupancy LDS-unconstrained
    __shared__ float s_red[4];

    const float TWO_PI_F = 6.2831853071795864769f;

    const int tid  = threadIdx.x;
    const int band = blockIdx.x;            // 0..5
    const int n    = blockIdx.y;
    const int r0   = band * 12;
    const int R    = (band == 5) ? 4 : 12;
    const int rows_l   = R + 2;             // staged rows needed (14 or 6)
    const int n_active = (R == 12) ? 256 : 86;
    const float* xn  = x + n * 4096;
    const float* h1n = h1g + (size_t)n * 131072;   // 64 rows * 2048 floats

    // active-site mapping: rows 3g,3g+1,3g+2 hold 22,21,21 actives, col≡row mod 3
    int g3 = tid >> 6, u = tid & 63;
    int rsel  = (u >= 22) + (u >= 43);
    int ubase = (rsel == 2) ? 43 : ((rsel == 1) ? 22 : 0);
    int rr = 3 * g3 + rsel;                 // local band row
    int cc = 3 * (u - ubase) + rsel;        // global col
    bool is_act = (tid < n_active);
    int jm = (cc + 63) & 63, jp = (cc + 1) & 63;   // wrapped window cols

    // LDS gather element offsets (site gi=r0+rr -> staged rows rr..rr+2)
    const int ex0 = rr * 64 + jm, ex1 = rr * 64 + cc, ex2 = rr * 64 + jp;

    // ---- staging geometry: slots s = tid, tid+256, tid+512, tid+768(<896) ----
    // LDS layout: [c(0..3)][row(0..13)][col(0..63)]; slot s = c*224 + r*16 + q
    // (precomputed once -> no division/modulo inside the chunk loop)
    const int s0 = tid, s1 = tid + 256, s2 = tid + 512, s3 = tid + 768;
    const int c_0 = s0 / 224, t0_ = s0 - c_0 * 224, r_0 = t0_ >> 4, q_0 = t0_ & 15;
    const int c_1 = s1 / 224, t1_ = s1 - c_1 * 224, r_1 = t1_ >> 4, q_1 = t1_ & 15;
    const int c_2 = s2 / 224, t2_ = s2 - c_2 * 224, r_2 = t2_ >> 4, q_2 = t2_ & 15;
    const int c_3 = s3 / 224, t3_ = s3 - c_3 * 224, r_3 = t3_ >> 4, q_3 = t3_ & 15;
    const float* gp0 = h1n + (size_t)((r0 - 1 + r_0) & 63) * 2048 + c_0 * 64 + (q_0 << 2);
    const float* gp1 = h1n + (size_t)((r0 - 1 + r_1) & 63) * 2048 + c_1 * 64 + (q_1 << 2);
    const float* gp2 = h1n + (size_t)((r0 - 1 + r_2) & 63) * 2048 + c_2 * 64 + (q_2 << 2);
    const float* gp3 = h1n + (size_t)((r0 - 1 + r_3) & 63) * 2048 + c_3 * 64 + (q_3 << 2);
    const bool lv0 = (r_0 < rows_l);
    const bool lv1 = (r_1 < rows_l);
    const bool lv2 = (r_2 < rows_l);
    const bool lv3 = (tid < 128) && (r_3 < rows_l);

    // prefetched chunk held in registers across compute (T14 issue-early/write-late)
    float4 f0 = make_float4(0.f,0.f,0.f,0.f), f1 = f0, f2 = f0, f3 = f0;

#define K2LOAD(CB) do {                                              \
        if (lv0) f0 = *(const float4*)(gp0 + (CB) * 64);             \
        if (lv1) f1 = *(const float4*)(gp1 + (CB) * 64);             \
        if (lv2) f2 = *(const float4*)(gp2 + (CB) * 64);             \
        if (lv3) f3 = *(const float4*)(gp3 + (CB) * 64);             \
    } while (0)

#define K2WRITE() do {                                               \
        if (lv0) *(float4*)(&s_h1[s0 * 4]) = f0;                     \
        if (lv1) *(float4*)(&s_h1[s1 * 4]) = f1;                     \
        if (lv2) *(float4*)(&s_h1[s2 * 4]) = f2;                     \
        if (lv3) *(float4*)(&s_h1[s3 * 4]) = f3;                     \
    } while (0)

    float acc[C2];
    #pragma unroll
    for (int co = 0; co < C2; ++co) acc[co] = c2b[co];

    // ---- prologue: load chunk 0 into registers ----
    K2LOAD(0);

    // ---- main loop: write staged regs -> barrier -> prefetch next -> compute ----
    #pragma unroll 1
    for (int c0 = 0; c0 < C1; c0 += K2CH) {
        __syncthreads();                    // (a) all waves done reading prev chunk
        K2WRITE();                          // regs -> LDS (vmcnt long since drained)
        __syncthreads();                    // (b) chunk c0 visible to all
        if (c0 + K2CH < C1) K2LOAD(c0 + K2CH);   // latency hidden under 900 FMAs
        if (is_act) K2_COMPUTE(c0)
    }
#undef K2LOAD
#undef K2WRITE

    // ---- passive/frozen pass-through ----
    float* outn = out_fx + n * 4096;
    for (int idx = tid; idx < R * 64; idx += 256) {
        int lr = idx >> 6, c = idx & 63;
        int gi = r0 + lr;
        int pat = (gi + 2 * c) % 3;
        float xv = xn[gi * 64 + c];
        if (pat != 0) outn[gi * 64 + c] = xv;
    }

    // ---- spline at the active site (exact math, r4-identical) ----
    float lj_val = 0.0f;
    if (is_act) {
        int gi = r0 + rr;
        float xv = xn[gi * 64 + cc];

        float kx[NB + 1], ky[NB + 1], sar[NB + 1];
        {
            float m = acc[0];
            #pragma unroll
            for (int qi = 1; qi < NB; ++qi) m = fmaxf(m, acc[qi]);
            float e[NB], ssum = 0.0f;
            #pragma unroll
            for (int qi = 0; qi < NB; ++qi) { e[qi] = expf(acc[qi] - m); ssum += e[qi]; }
            float inv = TWO_PI_F / ssum;
            float run = 0.0f;
            kx[0] = 0.0f;
            #pragma unroll
            for (int qi = 0; qi < NB; ++qi) { run += e[qi]; kx[qi + 1] = run * inv; }
        }
        {
            float m = acc[NB];
            #pragma unroll
            for (int qi = 1; qi < NB; ++qi) m = fmaxf(m, acc[NB + qi]);
            float e[NB], ssum = 0.0f;
            #pragma unroll
            for (int qi = 0; qi < NB; ++qi) { e[qi] = expf(acc[NB + qi] - m); ssum += e[qi]; }
            float inv = TWO_PI_F / ssum;
            float run = 0.0f;
            ky[0] = 0.0f;
            #pragma unroll
            for (int qi = 0; qi < NB; ++qi) { run += e[qi]; ky[qi + 1] = run * inv; }
        }
        #pragma unroll
        for (int qi = 0; qi < NB; ++qi) sar[qi] = softplus_f(acc[2 * NB + qi]);
        sar[NB] = sar[0];
        float t_out = acc[3 * NB];

        float x1 = pos_mod_2pi(xv);
        int k = 0;
        #pragma unroll
        for (int qi = 1; qi <= NB - 1; ++qi) k += (x1 >= kx[qi]) ? 1 : 0;

        float kxk = 0.f, kxk1 = 0.f, kyk = 0.f, kyk1 = 0.f, sk = 0.f, sk1 = 0.f;
        #pragma unroll
        for (int qi = 0; qi <= NB; ++qi) {
            if (qi == k)     { kxk = kx[qi];  kyk = ky[qi];  sk  = sar[qi]; }
            if (qi == k + 1) { kxk1 = kx[qi]; kyk1 = ky[qi]; sk1 = sar[qi]; }
        }

        float wk = kxk1 - kxk;
        float hk = kyk1 - kyk;
        float slope = hk / wk;
        float xi = (x1 - kxk) / wk;
        xi = fminf(fmaxf(xi, 0.0f), 1.0f);
        float om = 1.0f - xi;
        float den = slope + (sk1 + sk - 2.0f * slope) * xi * om;
        float y = kyk + hk * (slope * xi * xi + sk * xi * om) / den;
        float num = slope * slope * (sk1 * xi * xi + 2.0f * slope * xi * om + sk * om * om);
        lj_val = logf(num) - 2.0f * logf(den);

        outn[gi * 64 + cc] = pos_mod_2pi(y + t_out);
    }

    // ---- logJ: wave shuffle -> LDS -> one atomic per block ----
    float r = lj_val;
    #pragma unroll
    for (int off = 32; off > 0; off >>= 1) r += __shfl_down(r, off, 64);
    int lane = tid & 63, wv = tid >> 6;
    if (lane == 0) s_red[wv] = r;
    __syncthreads();
    if (tid == 0)
        atomicAdd(&out_logJ[n], s_red[0] + s_red[1] + s_red[2] + s_red[3]);
}

// ================= fallback: round-4 fused kernel (if ws too small) =================
#define CHUNK 8
#define ICOLS 68
#define ISTR  69
#define IROWSMAX 16
#define HCOLS 66
#define HSTR  67
#define HPLANE 945

__global__ __launch_bounds__(256, 4) void csplaq_v4_kernel(
    const float* __restrict__ x,
    const float* __restrict__ c1w, const float* __restrict__ c1b,
    const float* __restrict__ c2w, const float* __restrict__ c2b,
    float* __restrict__ out_fx, float* __restrict__ out_logJ)
{
    __shared__ float s_cos[IROWSMAX * ISTR];
    __shared__ float s_sin[IROWSMAX * ISTR];
    __shared__ float s_h1[CHUNK * HPLANE];
    __shared__ float s_red[4];

    const float TWO_PI_F = 6.2831853071795864769f;
    const int tid  = threadIdx.x;
    const int band = blockIdx.x;
    const int n    = blockIdx.y;
    const int r0   = band * 12;
    const int R    = (band == 5) ? 4 : 12;
    const int rows_in  = R + 4;
    const int nsite_h  = (R + 2) * HCOLS;
    const int n_active = (R == 12) ? 256 : 86;
    const float* xn = x + n * Ld * Ld;

    for (int idx = tid; idx < rows_in * ICOLS; idx += 256) {
        int li = idx / ICOLS, uu = idx - li * ICOLS;
        int gi = (r0 - 2 + li) & 63;
        int gj = (uu - 2) & 63;
        float xv = xn[gi * Ld + gj];
        int pat = (gi + 2 * gj) % 3;
        float sv, cv;
        sincosf(xv, &sv, &cv);
        float fz = (pat == 2) ? 1.0f : 0.0f;
        s_cos[li * ISTR + uu] = fz * cv;
        s_sin[li * ISTR + uu] = fz * sv;
    }

    int g3 = tid >> 6, u = tid & 63;
    int rsel  = (u >= 22) + (u >= 43);
    int ubase = (rsel == 2) ? 43 : ((rsel == 1) ? 22 : 0);
    int rr = 3 * g3 + rsel;
    int cc = 3 * (u - ubase) + rsel;
    bool is_act = (tid < n_active);

    float acc[C2];
    #pragma unroll
    for (int co = 0; co < C2; ++co) acc[co] = c2b[co];

    for (int c0 = 0; c0 < C1; c0 += CHUNK) {
        __syncthreads();
        for (int s = tid; s < nsite_h; s += 256) {
            int h = s / HCOLS, j = s - h * HCOLS;
            float v[18];
            #pragma unroll
            for (int di = 0; di < 3; ++di)
                #pragma unroll
                for (int dj = 0; dj < 3; ++dj) {
                    int a = (h + di) * ISTR + (j + dj);
                    v[di * 3 + dj]     = s_cos[a];
                    v[9 + di * 3 + dj] = s_sin[a];
                }
            #pragma unroll
            for (int c = 0; c < CHUNK; ++c) {
                const float* w = c1w + (c0 + c) * 18;
                float a1 = c1b[c0 + c];
                #pragma unroll
                for (int t = 0; t < 9; ++t) {
                    a1 = fmaf(v[t],     w[t],     a1);
                    a1 = fmaf(v[9 + t], w[9 + t], a1);
                }
                s_h1[c * HPLANE + h * HSTR + j] = gelu_tanh(a1);
            }
        }
        __syncthreads();
        if (is_act) {
            #pragma unroll 1
            for (int c = 0; c < CHUNK; ++c) {
                int ci = c0 + c;
                float v[9];
                const float* hp = s_h1 + c * HPLANE + rr * HSTR + cc;
                #pragma unroll
                for (int di = 0; di < 3; ++di)
                    #pragma unroll
                    for (int dj = 0; dj < 3; ++dj)
                        v[di * 3 + dj] = hp[di * HSTR + dj];
                const float* wp = c2w + ci * 9;
                #pragma unroll
                for (int co = 0; co < C2; ++co) {
                    const float* w = wp + co * (C1 * 9);
                    float a2 = acc[co];
                    #pragma unroll
                    for (int t = 0; t < 9; ++t) a2 = fmaf(v[t], w[t], a2);
                    acc[co] = a2;
                }
            }
        }
    }

    float* outn = out_fx + n * Ld * Ld;
    for (int idx = tid; idx < R * 64; idx += 256) {
        int lr = idx >> 6, c = idx & 63;
        int gi = r0 + lr;
        int pat = (gi + 2 * c) % 3;
        float xv = xn[gi * Ld + c];
        if (pat != 0) outn[gi * Ld + c] = xv;
    }

    float lj_val = 0.0f;
    if (is_act) {
        int gi = r0 + rr;
        float xv = xn[gi * Ld + cc];
        float kx[NB + 1], ky[NB + 1], sar[NB + 1];
        {
            float m = acc[0];
            #pragma unroll
            for (int q = 1; q < NB; ++q) m = fmaxf(m, acc[q]);
            float e[NB], ssum = 0.0f;
            #pragma unroll
            for (int q = 0; q < NB; ++q) { e[q] = expf(acc[q] - m); ssum += e[q]; }
            float inv = TWO_PI_F / ssum;
            float run = 0.0f;
            kx[0] = 0.0f;
            #pragma unroll
            for (int q = 0; q < NB; ++q) { run += e[q]; kx[q + 1] = run * inv; }
        }
        {
            float m = acc[NB];
            #pragma unroll
            for (int q = 1; q < NB; ++q) m = fmaxf(m, acc[NB + q]);
            float e[NB], ssum = 0.0f;
            #pragma unroll
            for (int q = 0; q < NB; ++q) { e[q] = expf(acc[NB + q] - m); ssum += e[q]; }
            float inv = TWO_PI_F / ssum;
            float run = 0.0f;
            ky[0] = 0.0f;
            #pragma unroll
            for (int q = 0; q < NB; ++q) { run += e[q]; ky[q + 1] = run * inv; }
        }
        #pragma unroll
        for (int q = 0; q < NB; ++q) sar[q] = softplus_f(acc[2 * NB + q]);
        sar[NB] = sar[0];
        float t_out = acc[3 * NB];

        float x1 = pos_mod_2pi(xv);
        int k = 0;
        #pragma unroll
        for (int q = 1; q <= NB - 1; ++q) k += (x1 >= kx[q]) ? 1 : 0;

        float kxk = 0.f, kxk1 = 0.f, kyk = 0.f, kyk1 = 0.f, sk = 0.f, sk1 = 0.f;
        #pragma unroll
        for (int q = 0; q <= NB; ++q) {
            if (q == k)     { kxk = kx[q];  kyk = ky[q];  sk  = sar[q]; }
            if (q == k + 1) { kxk1 = kx[q]; kyk1 = ky[q]; sk1 = sar[q]; }
        }

        float wk = kxk1 - kxk;
        float hk = kyk1 - kyk;
        float slope = hk / wk;
        float xi = (x1 - kxk) / wk;
        xi = fminf(fmaxf(xi, 0.0f), 1.0f);
        float om = 1.0f - xi;
        float den = slope + (sk1 + sk - 2.0f * slope) * xi * om;
        float y = kyk + hk * (slope * xi * xi + sk * xi * om) / den;
        float num = slope * slope * (sk1 * xi * xi + 2.0f * slope * xi * om + sk * om * om);
        lj_val = logf(num) - 2.0f * logf(den);

        outn[gi * Ld + cc] = pos_mod_2pi(y + t_out);
    }

    float r = lj_val;
    #pragma unroll
    for (int off = 32; off > 0; off >>= 1) r += __shfl_down(r, off, 64);
    int lane = tid & 63, wv = tid >> 6;
    if (lane == 0) s_red[wv] = r;
    __syncthreads();
    if (tid == 0)
        atomicAdd(&out_logJ[n], s_red[0] + s_red[1] + s_red[2] + s_red[3]);
}

extern "C" void kernel_launch(void* const* d_in, const int* in_sizes, int n_in,
                              void* d_out, int out_size, void* d_ws, size_t ws_size,
                              hipStream_t stream) {
    const float* x   = (const float*)d_in[0];
    // d_in[1..3] masks: recomputed analytically ((i+2j)%3) -> exact
    const float* c1w = (const float*)d_in[4];
    const float* c1b = (const float*)d_in[5];
    const float* c2w = (const float*)d_in[6];
    const float* c2b = (const float*)d_in[7];

    float* out_fx   = (float*)d_out;
    float* out_logJ = out_fx + (size_t)Nn * Ld * Ld;

    hipMemsetAsync(out_logJ, 0, Nn * sizeof(float), stream);

    const size_t h1_bytes = (size_t)Nn * C1 * Ld * Ld * sizeof(float);  // 256 MiB
    if (ws_size >= h1_bytes) {
        float* h1g = (float*)d_ws;
        dim3 g1(16, Nn);
        k1_conv1_kernel<<<g1, 256, 0, stream>>>(x, c1w, c1b, h1g);
        dim3 g2(6, Nn);
        k2_conv2_spline_kernel<<<g2, 256, 0, stream>>>(x, h1g, c2w, c2b, out_fx, out_logJ);
    } else {
        dim3 grid(6, Nn);
        csplaq_v4_kernel<<<grid, 256, 0, stream>>>(x, c1w, c1b, c2w, c2b, out_fx, out_logJ);
    }
}

// Round 5
// 584.341 us; speedup vs baseline: 1.0461x; 1.0461x over previous
//
#include <hip/hip_runtime.h>
#include <math.h>

#define Nn 512
#define Ld 64
#define NB 8
#define C1 32
#define C2 25      // 3*NB+1

// ---- exact math helpers ----
__device__ __forceinline__ float gelu_tanh(float a) {
    float a3 = a * a * a;
    float t = tanhf(0.7978845608028654f * (a + 0.044715f * a3));
    return 0.5f * a * (1.0f + t);
}

// algebraically identical to gelu_tanh: 0.5a(1+tanh(u)) == a/(1+exp(-2u))
__device__ __forceinline__ float gelu_fast(float a) {
    float a3 = a * a * a;
    float u2 = 1.5957691216057308f * (a + 0.044715f * a3);   // 2*0.79788456...
    return a / (1.0f + __expf(-u2));
}

__device__ __forceinline__ float softplus_f(float v) {
    return (v > 0.0f) ? v + log1pf(expf(-v)) : log1pf(expf(v));
}

__device__ __forceinline__ float pos_mod_2pi(float v) {
    const float T = 6.2831853071795864769f;
    float r = fmodf(v, T);
    if (r < 0.0f) r += T;
    return r;
}

// async 16B/lane global->LDS DMA. HW semantics (m104/m108): LDS dest =
// readfirstlane(lds_ptr) + lane*16; global src is per-lane. Callers MUST pass a
// wave-uniform lds_ptr and keep exec non-divergent across the call.
__device__ __forceinline__ void async_copy16(const float* g, float* l) {
    __builtin_amdgcn_global_load_lds(
        (const __attribute__((address_space(1))) void*)g,
        (__attribute__((address_space(3))) void*)l, 16, 0, 0);
}

// ================= K1: conv1 + gelu -> global h1 [n][row][c][col] =================
// layout: h1g[((n*64 + row)*32 + c)*64 + col]  -> per wave: 32 x 256B sequential (8KB/row)
__global__ __launch_bounds__(256, 8) void k1_conv1_kernel(
    const float* __restrict__ x,
    const float* __restrict__ c1w, const float* __restrict__ c1b,
    float* __restrict__ h1g)
{
    __shared__ float s_cos[8 * 69];
    __shared__ float s_sin[8 * 69];

    const int tid = threadIdx.x;
    const int rb  = blockIdx.x;      // 0..15 -> 4-row band
    const int n   = blockIdx.y;
    const int r0k = rb * 4;
    const float* xn = x + n * 4096;

    // stage frozen-masked cos/sin: rows r0k-2..r0k+5, cols -2..65 (wrapped)
    for (int idx = tid; idx < 8 * 68; idx += 256) {
        int li = idx / 68, lj = idx - li * 68;
        int gi = (r0k - 2 + li) & 63;
        int gj = (lj - 2) & 63;
        float xv = xn[gi * 64 + gj];
        int pat = (gi + 2 * gj) % 3;
        float sv, cv;
        sincosf(xv, &sv, &cv);
        float fz = (pat == 2) ? 1.0f : 0.0f;
        s_cos[li * 69 + lj] = fz * cv;
        s_sin[li * 69 + lj] = fz * sv;
    }
    __syncthreads();

    const int gj = tid & 63, lrow = tid >> 6;
    const int gi = r0k + lrow;

    float v[18];
    #pragma unroll
    for (int di = 0; di < 3; ++di)
        #pragma unroll
        for (int dj = 0; dj < 3; ++dj) {
            int a = (lrow + 1 + di) * 69 + (gj + 1 + dj);
            v[di * 3 + dj]     = s_cos[a];
            v[9 + di * 3 + dj] = s_sin[a];
        }

    float* outp = h1g + ((size_t)n * 64 + gi) * 2048 + gj;
    #pragma unroll 4
    for (int c = 0; c < C1; ++c) {
        const float* w = c1w + c * 18;   // uniform -> s_load
        float a1 = c1b[c];
        #pragma unroll
        for (int t = 0; t < 9; ++t) {    // cos/sin interleaved per tap (r4 order)
            a1 = fmaf(v[t],     w[t],     a1);
            a1 = fmaf(v[9 + t], w[9 + t], a1);
        }
        outp[(size_t)c * 64] = gelu_fast(a1);   // wave: 64 consecutive floats per c
    }
}

// ================= K2: conv2 + spline + passthrough + logJ =================
#define K2CH 4
#define K2BUF 3584             // floats per buffer: 14 rows * (4 ch * 64 cols) = 14336 B

// LDS layout per buffer: [row 0..13][c 0..3][col 0..63]; element = row*256 + c*64 + col
#define K2_COMPUTE(BUF, CBASE)                                            \
    {                                                                     \
        _Pragma("unroll")                                                 \
        for (int c = 0; c < K2CH; ++c) {                                  \
            const int eb = (BUF) + c * 64;                                \
            float v0 = s_h1[eb + ex0];                                    \
            float v1 = s_h1[eb + ex1];                                    \
            float v2 = s_h1[eb + ex2];                                    \
            float v3 = s_h1[eb + ex0 + 256];                              \
            float v4 = s_h1[eb + ex1 + 256];                              \
            float v5 = s_h1[eb + ex2 + 256];                              \
            float v6 = s_h1[eb + ex0 + 512];                              \
            float v7 = s_h1[eb + ex1 + 512];                              \
            float v8 = s_h1[eb + ex2 + 512];                              \
            const float* wpc = c2w + ((CBASE) + c) * 9;                   \
            _Pragma("unroll")                                             \
            for (int co = 0; co < C2; ++co) {                             \
                const float* w = wpc + co * (C1 * 9);  /* uniform */      \
                float a2 = acc[co];                                       \
                a2 = fmaf(v0, w[0], a2);                                  \
                a2 = fmaf(v1, w[1], a2);                                  \
                a2 = fmaf(v2, w[2], a2);                                  \
                a2 = fmaf(v3, w[3], a2);                                  \
                a2 = fmaf(v4, w[4], a2);                                  \
                a2 = fmaf(v5, w[5], a2);                                  \
                a2 = fmaf(v6, w[6], a2);                                  \
                a2 = fmaf(v7, w[7], a2);                                  \
                a2 = fmaf(v8, w[8], a2);                                  \
                acc[co] = a2;                                             \
            }                                                             \
        }                                                                 \
    }

__global__ __launch_bounds__(256, 5) void k2_conv2_spline_kernel(
    const float* __restrict__ x, const float* __restrict__ h1g,
    const float* __restrict__ c2w, const float* __restrict__ c2b,
    float* __restrict__ out_fx, float* __restrict__ out_logJ)
{
    __shared__ float s_h1[2 * K2BUF];   // 28672 B double buffer -> 5 blocks/CU
    __shared__ float s_red[4];

    const float TWO_PI_F = 6.2831853071795864769f;

    const int tid  = threadIdx.x;
    const int band = blockIdx.x;            // 0..5
    const int n    = blockIdx.y;
    const int r0   = band * 12;
    const int R    = (band == 5) ? 4 : 12;
    const int rows_l   = R + 2;             // staged rows needed (14 or 6)
    const int n_active = (R == 12) ? 256 : 86;
    const float* xn  = x + n * 4096;
    const float* h1n = h1g + (size_t)n * 131072;   // 64 rows * 2048 floats

    // active-site mapping: rows 3g,3g+1,3g+2 hold 22,21,21 actives, col≡row mod 3
    int g3 = tid >> 6, u = tid & 63;
    int rsel  = (u >= 22) + (u >= 43);
    int ubase = (rsel == 2) ? 43 : ((rsel == 1) ? 22 : 0);
    int rr = 3 * g3 + rsel;                 // local band row
    int cc = 3 * (u - ubase) + rsel;        // global col
    bool is_act = (tid < n_active);
    int jm = (cc + 63) & 63, jp = (cc + 1) & 63;   // wrapped window cols

    // LDS gather element offsets (site gi=r0+rr -> staged rows rr..rr+2)
    const int ex0 = rr * 256 + jm, ex1 = rr * 256 + cc, ex2 = rr * 256 + jp;

    // ---- DMA staging geometry: one chunk-row = 4ch x 64col = 1KB = one wave op ----
    // wave w stages rows w, w+4, w+8 (+ row 12+w if w<2). All conditions wave-uniform.
    const int w    = tid >> 6;
    const int lane = tid & 63;
    const int row0 = w, row1 = w + 4, row2 = w + 8, row3 = 12 + w;
    // per-lane global sources (lane*4 floats = 16B/lane); +CB*64 floats per chunk
    const float* gs0 = h1n + (size_t)((r0 - 1 + row0) & 63) * 2048 + lane * 4;
    const float* gs1 = h1n + (size_t)((r0 - 1 + row1) & 63) * 2048 + lane * 4;
    const float* gs2 = h1n + (size_t)((r0 - 1 + row2) & 63) * 2048 + lane * 4;
    const float* gs3 = h1n + (size_t)((r0 - 1 + row3) & 63) * 2048 + lane * 4;
    // wave-uniform guards (rows beyond rows_l are never read by compute)
    const bool sv1 = (row1 < rows_l);
    const bool sv2 = (row2 < rows_l);
    const bool sv3 = (w < 2) && (row3 < rows_l);

#define STAGE(BOFS, CB) do {                                                  \
        async_copy16(gs0 + (CB) * 64, s_h1 + (BOFS) + row0 * 256);            \
        if (sv1) async_copy16(gs1 + (CB) * 64, s_h1 + (BOFS) + row1 * 256);   \
        if (sv2) async_copy16(gs2 + (CB) * 64, s_h1 + (BOFS) + row2 * 256);   \
        if (sv3) async_copy16(gs3 + (CB) * 64, s_h1 + (BOFS) + row3 * 256);   \
    } while (0)

    float acc[C2];
    #pragma unroll
    for (int co = 0; co < C2; ++co) acc[co] = c2b[co];

    // ---- prologue: DMA chunk 0 -> buf0 ----
    STAGE(0, 0);
    __syncthreads();                        // compiler drains vmcnt before barrier

    // ---- main loop: issue next-chunk DMA, compute current, barrier ----
    #pragma unroll 1
    for (int c0 = 0; c0 < C1; c0 += 2 * K2CH) {
        STAGE(K2BUF, c0 + K2CH);            // chunk c0+4 -> buf1 (c0+4 <= 28 < 32)
        if (is_act) K2_COMPUTE(0, c0)       // ~1800 cyc covers DMA latency
        __syncthreads();                    // vmcnt drained -> buf1 ready
        if (c0 + 2 * K2CH < C1) STAGE(0, c0 + 2 * K2CH);   // chunk c0+8 -> buf0
        if (is_act) K2_COMPUTE(K2BUF, c0 + K2CH)
        __syncthreads();                    // buf0 ready for next iter
    }
#undef STAGE

    // ---- passive/frozen pass-through ----
    float* outn = out_fx + n * 4096;
    for (int idx = tid; idx < R * 64; idx += 256) {
        int lr = idx >> 6, c = idx & 63;
        int gi = r0 + lr;
        int pat = (gi + 2 * c) % 3;
        float xv = xn[gi * 64 + c];
        if (pat != 0) outn[gi * 64 + c] = xv;
    }

    // ---- spline at the active site (exact math, r4-identical) ----
    float lj_val = 0.0f;
    if (is_act) {
        int gi = r0 + rr;
        float xv = xn[gi * 64 + cc];

        float kx[NB + 1], ky[NB + 1], sar[NB + 1];
        {
            float m = acc[0];
            #pragma unroll
            for (int qi = 1; qi < NB; ++qi) m = fmaxf(m, acc[qi]);
            float e[NB], ssum = 0.0f;
            #pragma unroll
            for (int qi = 0; qi < NB; ++qi) { e[qi] = expf(acc[qi] - m); ssum += e[qi]; }
            float inv = TWO_PI_F / ssum;
            float run = 0.0f;
            kx[0] = 0.0f;
            #pragma unroll
            for (int qi = 0; qi < NB; ++qi) { run += e[qi]; kx[qi + 1] = run * inv; }
        }
        {
            float m = acc[NB];
            #pragma unroll
            for (int qi = 1; qi < NB; ++qi) m = fmaxf(m, acc[NB + qi]);
            float e[NB], ssum = 0.0f;
            #pragma unroll
            for (int qi = 0; qi < NB; ++qi) { e[qi] = expf(acc[NB + qi] - m); ssum += e[qi]; }
            float inv = TWO_PI_F / ssum;
            float run = 0.0f;
            ky[0] = 0.0f;
            #pragma unroll
            for (int qi = 0; qi < NB; ++qi) { run += e[qi]; ky[qi + 1] = run * inv; }
        }
        #pragma unroll
        for (int qi = 0; qi < NB; ++qi) sar[qi] = softplus_f(acc[2 * NB + qi]);
        sar[NB] = sar[0];
        float t_out = acc[3 * NB];

        float x1 = pos_mod_2pi(xv);
        int k = 0;
        #pragma unroll
        for (int qi = 1; qi <= NB - 1; ++qi) k += (x1 >= kx[qi]) ? 1 : 0;

        float kxk = 0.f, kxk1 = 0.f, kyk = 0.f, kyk1 = 0.f, sk = 0.f, sk1 = 0.f;
        #pragma unroll
        for (int qi = 0; qi <= NB; ++qi) {
            if (qi == k)     { kxk = kx[qi];  kyk = ky[qi];  sk  = sar[qi]; }
            if (qi == k + 1) { kxk1 = kx[qi]; kyk1 = ky[qi]; sk1 = sar[qi]; }
        }

        float wk = kxk1 - kxk;
        float hk = kyk1 - kyk;
        float slope = hk / wk;
        float xi = (x1 - kxk) / wk;
        xi = fminf(fmaxf(xi, 0.0f), 1.0f);
        float om = 1.0f - xi;
        float den = slope + (sk1 + sk - 2.0f * slope) * xi * om;
        float y = kyk + hk * (slope * xi * xi + sk * xi * om) / den;
        float num = slope * slope * (sk1 * xi * xi + 2.0f * slope * xi * om + sk * om * om);
        lj_val = logf(num) - 2.0f * logf(den);

        outn[gi * 64 + cc] = pos_mod_2pi(y + t_out);
    }

    // ---- logJ: wave shuffle -> LDS -> one atomic per block ----
    float r = lj_val;
    #pragma unroll
    for (int off = 32; off > 0; off >>= 1) r += __shfl_down(r, off, 64);
    int lane2 = tid & 63, wv = tid >> 6;
    if (lane2 == 0) s_red[wv] = r;
    __syncthreads();
    if (tid == 0)
        atomicAdd(&out_logJ[n], s_red[0] + s_red[1] + s_red[2] + s_red[3]);
}

// ================= fallback: round-4 fused kernel (if ws too small) =================
#define CHUNK 8
#define ICOLS 68
#define ISTR  69
#define IROWSMAX 16
#define HCOLS 66
#define HSTR  67
#define HPLANE 945

__global__ __launch_bounds__(256, 4) void csplaq_v4_kernel(
    const float* __restrict__ x,
    const float* __restrict__ c1w, const float* __restrict__ c1b,
    const float* __restrict__ c2w, const float* __restrict__ c2b,
    float* __restrict__ out_fx, float* __restrict__ out_logJ)
{
    __shared__ float s_cos[IROWSMAX * ISTR];
    __shared__ float s_sin[IROWSMAX * ISTR];
    __shared__ float s_h1[CHUNK * HPLANE];
    __shared__ float s_red[4];

    const float TWO_PI_F = 6.2831853071795864769f;
    const int tid  = threadIdx.x;
    const int band = blockIdx.x;
    const int n    = blockIdx.y;
    const int r0   = band * 12;
    const int R    = (band == 5) ? 4 : 12;
    const int rows_in  = R + 4;
    const int nsite_h  = (R + 2) * HCOLS;
    const int n_active = (R == 12) ? 256 : 86;
    const float* xn = x + n * Ld * Ld;

    for (int idx = tid; idx < rows_in * ICOLS; idx += 256) {
        int li = idx / ICOLS, uu = idx - li * ICOLS;
        int gi = (r0 - 2 + li) & 63;
        int gj = (uu - 2) & 63;
        float xv = xn[gi * Ld + gj];
        int pat = (gi + 2 * gj) % 3;
        float sv, cv;
        sincosf(xv, &sv, &cv);
        float fz = (pat == 2) ? 1.0f : 0.0f;
        s_cos[li * ISTR + uu] = fz * cv;
        s_sin[li * ISTR + uu] = fz * sv;
    }

    int g3 = tid >> 6, u = tid & 63;
    int rsel  = (u >= 22) + (u >= 43);
    int ubase = (rsel == 2) ? 43 : ((rsel == 1) ? 22 : 0);
    int rr = 3 * g3 + rsel;
    int cc = 3 * (u - ubase) + rsel;
    bool is_act = (tid < n_active);

    float acc[C2];
    #pragma unroll
    for (int co = 0; co < C2; ++co) acc[co] = c2b[co];

    for (int c0 = 0; c0 < C1; c0 += CHUNK) {
        __syncthreads();
        for (int s = tid; s < nsite_h; s += 256) {
            int h = s / HCOLS, j = s - h * HCOLS;
            float v[18];
            #pragma unroll
            for (int di = 0; di < 3; ++di)
                #pragma unroll
                for (int dj = 0; dj < 3; ++dj) {
                    int a = (h + di) * ISTR + (j + dj);
                    v[di * 3 + dj]     = s_cos[a];
                    v[9 + di * 3 + dj] = s_sin[a];
                }
            #pragma unroll
            for (int c = 0; c < CHUNK; ++c) {
                const float* w = c1w + (c0 + c) * 18;
                float a1 = c1b[c0 + c];
                #pragma unroll
                for (int t = 0; t < 9; ++t) {
                    a1 = fmaf(v[t],     w[t],     a1);
                    a1 = fmaf(v[9 + t], w[9 + t], a1);
                }
                s_h1[c * HPLANE + h * HSTR + j] = gelu_tanh(a1);
            }
        }
        __syncthreads();
        if (is_act) {
            #pragma unroll 1
            for (int c = 0; c < CHUNK; ++c) {
                int ci = c0 + c;
                float v[9];
                const float* hp = s_h1 + c * HPLANE + rr * HSTR + cc;
                #pragma unroll
                for (int di = 0; di < 3; ++di)
                    #pragma unroll
                    for (int dj = 0; dj < 3; ++dj)
                        v[di * 3 + dj] = hp[di * HSTR + dj];
                const float* wp = c2w + ci * 9;
                #pragma unroll
                for (int co = 0; co < C2; ++co) {
                    const float* w = wp + co * (C1 * 9);
                    float a2 = acc[co];
                    #pragma unroll
                    for (int t = 0; t < 9; ++t) a2 = fmaf(v[t], w[t], a2);
                    acc[co] = a2;
                }
            }
        }
    }

    float* outn = out_fx + n * Ld * Ld;
    for (int idx = tid; idx < R * 64; idx += 256) {
        int lr = idx >> 6, c = idx & 63;
        int gi = r0 + lr;
        int pat = (gi + 2 * c) % 3;
        float xv = xn[gi * Ld + c];
        if (pat != 0) outn[gi * Ld + c] = xv;
    }

    float lj_val = 0.0f;
    if (is_act) {
        int gi = r0 + rr;
        float xv = xn[gi * Ld + cc];
        float kx[NB + 1], ky[NB + 1], sar[NB + 1];
        {
            float m = acc[0];
            #pragma unroll
            for (int q = 1; q < NB; ++q) m = fmaxf(m, acc[q]);
            float e[NB], ssum = 0.0f;
            #pragma unroll
            for (int q = 0; q < NB; ++q) { e[q] = expf(acc[q] - m); ssum += e[q]; }
            float inv = TWO_PI_F / ssum;
            float run = 0.0f;
            kx[0] = 0.0f;
            #pragma unroll
            for (int q = 0; q < NB; ++q) { run += e[q]; kx[q + 1] = run * inv; }
        }
        {
            float m = acc[NB];
            #pragma unroll
            for (int q = 1; q < NB; ++q) m = fmaxf(m, acc[NB + q]);
            float e[NB], ssum = 0.0f;
            #pragma unroll
            for (int q = 0; q < NB; ++q) { e[q] = expf(acc[NB + q] - m); ssum += e[q]; }
            float inv = TWO_PI_F / ssum;
            float run = 0.0f;
            ky[0] = 0.0f;
            #pragma unroll
            for (int q = 0; q < NB; ++q) { run += e[q]; ky[q + 1] = run * inv; }
        }
        #pragma unroll
        for (int q = 0; q < NB; ++q) sar[q] = softplus_f(acc[2 * NB + q]);
        sar[NB] = sar[0];
        float t_out = acc[3 * NB];

        float x1 = pos_mod_2pi(xv);
        int k = 0;
        #pragma unroll
        for (int q = 1; q <= NB - 1; ++q) k += (x1 >= kx[q]) ? 1 : 0;

        float kxk = 0.f, kxk1 = 0.f, kyk = 0.f, kyk1 = 0.f, sk = 0.f, sk1 = 0.f;
        #pragma unroll
        for (int q = 0; q <= NB; ++q) {
            if (q == k)     { kxk = kx[q];  kyk = ky[q];  sk  = sar[q]; }
            if (q == k + 1) { kxk1 = kx[q]; kyk1 = ky[q]; sk1 = sar[q]; }
        }

        float wk = kxk1 - kxk;
        float hk = kyk1 - kyk;
        float slope = hk / wk;
        float xi = (x1 - kxk) / wk;
        xi = fminf(fmaxf(xi, 0.0f), 1.0f);
        float om = 1.0f - xi;
        float den = slope + (sk1 + sk - 2.0f * slope) * xi * om;
        float y = kyk + hk * (slope * xi * xi + sk * xi * om) / den;
        float num = slope * slope * (sk1 * xi * xi + 2.0f * slope * xi * om + sk * om * om);
        lj_val = logf(num) - 2.0f * logf(den);

        outn[gi * Ld + cc] = pos_mod_2pi(y + t_out);
    }

    float r = lj_val;
    #pragma unroll
    for (int off = 32; off > 0; off >>= 1) r += __shfl_down(r, off, 64);
    int lane = tid & 63, wv = tid >> 6;
    if (lane == 0) s_red[wv] = r;
    __syncthreads();
    if (tid == 0)
        atomicAdd(&out_logJ[n], s_red[0] + s_red[1] + s_red[2] + s_red[3]);
}

extern "C" void kernel_launch(void* const* d_in, const int* in_sizes, int n_in,
                              void* d_out, int out_size, void* d_ws, size_t ws_size,
                              hipStream_t stream) {
    const float* x   = (const float*)d_in[0];
    // d_in[1..3] masks: recomputed analytically ((i+2j)%3) -> exact
    const float* c1w = (const float*)d_in[4];
    const float* c1b = (const float*)d_in[5];
    const float* c2w = (const float*)d_in[6];
    const float* c2b = (const float*)d_in[7];

    float* out_fx   = (float*)d_out;
    float* out_logJ = out_fx + (size_t)Nn * Ld * Ld;

    hipMemsetAsync(out_logJ, 0, Nn * sizeof(float), stream);

    const size_t h1_bytes = (size_t)Nn * C1 * Ld * Ld * sizeof(float);  // 256 MiB
    if (ws_size >= h1_bytes) {
        float* h1g = (float*)d_ws;
        dim3 g1(16, Nn);
        k1_conv1_kernel<<<g1, 256, 0, stream>>>(x, c1w, c1b, h1g);
        dim3 g2(6, Nn);
        k2_conv2_spline_kernel<<<g2, 256, 0, stream>>>(x, h1g, c2w, c2b, out_fx, out_logJ);
    } else {
        dim3 grid(6, Nn);
        csplaq_v4_kernel<<<grid, 256, 0, stream>>>(x, c1w, c1b, c2w, c2b, out_fx, out_logJ);
    }
}

// Round 7
// 387.611 us; speedup vs baseline: 1.5771x; 1.5075x over previous
//
#include <hip/hip_runtime.h>
#include <math.h>

#define Nn 512
#define Ld 64
#define NB 8
#define C1 32
#define C2 25      // 3*NB+1

// ---- exact math helpers (field-proven r1..r5) ----
// algebraically identical to tanh-gelu: 0.5a(1+tanh(u)) == a/(1+exp(-2u))
__device__ __forceinline__ float gelu_fast(float a) {
    float a3 = a * a * a;
    float u2 = 1.5957691216057308f * (a + 0.044715f * a3);   // 2*0.79788456...
    return a / (1.0f + __expf(-u2));
}

__device__ __forceinline__ float softplus_f(float v) {
    return (v > 0.0f) ? v + log1pf(expf(-v)) : log1pf(expf(v));
}

__device__ __forceinline__ float pos_mod_2pi(float v) {
    const float T = 6.2831853071795864769f;
    float r = fmodf(v, T);
    if (r < 0.0f) r += T;
    return r;
}

// ================= fused: conv1+gelu (LDS) -> conv2 -> spline -> fx,logJ ============
#define FCH 8          // conv1 channels per chunk (4 chunks of 8)
#define ISTR 67        // input frame stride: 66 cols (global -1..64) + 1 pad
#define IROWS 16       // max staged input rows (R+4)
#define HPLANE 896     // h1 plane per channel: 14 rows x 64 cols (global col, no halo)

// compute h1 for one site-slot S (h = S>>6 -> global row r0-1+h, j = S&63) over FCH
// channels of chunk c0. Input taps: staged rows h..h+2, staged cols j..j+2.
#define H1SLOT(S, B, V)                                                   \
    if (V) {                                                              \
        float vv[18];                                                     \
        _Pragma("unroll")                                                 \
        for (int di = 0; di < 3; ++di)                                    \
            _Pragma("unroll")                                             \
            for (int dj = 0; dj < 3; ++dj) {                              \
                int a = (B) + di * ISTR + dj;                             \
                vv[di * 3 + dj]     = s_cos[a];                           \
                vv[9 + di * 3 + dj] = s_sin[a];                           \
            }                                                             \
        _Pragma("unroll")                                                 \
        for (int c = 0; c < FCH; ++c) {                                   \
            const float* w = c1w + (c0 + c) * 18;   /* uniform s_load */  \
            float a1 = c1b[c0 + c];                                       \
            _Pragma("unroll")                                             \
            for (int t = 0; t < 9; ++t) {   /* cos/sin interleaved */     \
                a1 = fmaf(vv[t],     w[t],     a1);                       \
                a1 = fmaf(vv[9 + t], w[9 + t], a1);                       \
            }                                                             \
            s_h1[c * HPLANE + (S)] = gelu_fast(a1);                       \
        }                                                                 \
    }

// conv2 accumulate over FCH channels of chunk CBASE (proven r0/r5 pattern, 64-stride)
#define CONV2(CBASE)                                                      \
    {                                                                     \
        _Pragma("unroll 1")                                               \
        for (int c = 0; c < FCH; ++c) {                                   \
            const int eb = c * HPLANE;                                    \
            float v0 = s_h1[eb + ex0];                                    \
            float v1 = s_h1[eb + ex1];                                    \
            float v2 = s_h1[eb + ex2];                                    \
            float v3 = s_h1[eb + ex0 + 64];                               \
            float v4 = s_h1[eb + ex1 + 64];                               \
            float v5 = s_h1[eb + ex2 + 64];                               \
            float v6 = s_h1[eb + ex0 + 128];                              \
            float v7 = s_h1[eb + ex1 + 128];                              \
            float v8 = s_h1[eb + ex2 + 128];                              \
            const float* wpc = c2w + ((CBASE) + c) * 9;                   \
            _Pragma("unroll")                                             \
            for (int co = 0; co < C2; ++co) {                             \
                const float* w = wpc + co * (C1 * 9);  /* uniform */      \
                float a2 = acc[co];                                       \
                a2 = fmaf(v0, w[0], a2);                                  \
                a2 = fmaf(v1, w[1], a2);                                  \
                a2 = fmaf(v2, w[2], a2);                                  \
                a2 = fmaf(v3, w[3], a2);                                  \
                a2 = fmaf(v4, w[4], a2);                                  \
                a2 = fmaf(v5, w[5], a2);                                  \
                a2 = fmaf(v6, w[6], a2);                                  \
                a2 = fmaf(v7, w[7], a2);                                  \
                a2 = fmaf(v8, w[8], a2);                                  \
                acc[co] = a2;                                             \
            }                                                             \
        }                                                                 \
    }

__global__ __launch_bounds__(256, 4) void csplaq_fused_kernel(
    const float* __restrict__ x,
    const float* __restrict__ c1w, const float* __restrict__ c1b,
    const float* __restrict__ c2w, const float* __restrict__ c2b,
    float* __restrict__ out_fx, float* __restrict__ out_logJ)
{
    __shared__ float s_cos[IROWS * ISTR];   // 1072 f = 4288 B
    __shared__ float s_sin[IROWS * ISTR];   // 4288 B
    __shared__ float s_h1[FCH * HPLANE];    // 7168 f = 28672 B
    __shared__ float s_red[4];              // total ~37.3 KB -> 4 blocks/CU

    const float TWO_PI_F = 6.2831853071795864769f;

    const int tid  = threadIdx.x;
    const int band = blockIdx.x;            // 0..5
    const int n    = blockIdx.y;
    const int r0   = band * 12;
    const int R    = (band == 5) ? 4 : 12;
    const int rows_in = R + 4;              // staged input rows (16 or 8)
    const int rows_l  = R + 2;              // h1 rows (14 or 6)
    const int nsh     = rows_l * 64;        // h1 sites (896 or 384)
    const int n_active = (R == 12) ? 256 : 86;
    const float* xn = x + n * 4096;

    // ---- stage frozen-masked cos/sin: rows r0-2..r0+R+1, cols -1..64 (66) ----
    for (int idx = tid; idx < rows_in * 66; idx += 256) {
        int li = idx / 66, u = idx - li * 66;
        int gi = (r0 - 2 + li) & 63;
        int gj = (u - 1) & 63;
        float xv = xn[gi * 64 + gj];
        int pat = (gi + 2 * gj) % 3;
        float sv, cv;
        sincosf(xv, &sv, &cv);
        float fz = (pat == 2) ? 1.0f : 0.0f;
        s_cos[li * ISTR + u] = fz * cv;
        s_sin[li * ISTR + u] = fz * sv;
    }

    // ---- active-site mapping (proven): rows 3g..3g+2 hold 22,21,21 actives ----
    int g3 = tid >> 6, u = tid & 63;
    int rsel  = (u >= 22) + (u >= 43);
    int ubase = (rsel == 2) ? 43 : ((rsel == 1) ? 22 : 0);
    int rr = 3 * g3 + rsel;                 // local band row (site gi = r0+rr)
    int cc = 3 * (u - ubase) + rsel;        // global col
    bool is_act = (tid < n_active);
    int jm = (cc + 63) & 63, jp = (cc + 1) & 63;   // wrapped window cols

    // h1-plane gather offsets: site row gi=r0+rr -> plane rows rr..rr+2
    const int ex0 = rr * 64 + jm, ex1 = rr * 64 + cc, ex2 = rr * 64 + jp;

    // ---- h1 slot decomposition (shift-only, loop-invariant) ----
    const int sA = tid, sB = tid + 256, sC = tid + 512, sD = tid + 768;
    const int bA = (sA >> 6) * ISTR + (sA & 63);
    const int bB = (sB >> 6) * ISTR + (sB & 63);
    const int bC = (sC >> 6) * ISTR + (sC & 63);
    const int bD = (sD >> 6) * ISTR + (sD & 63);
    const bool vA = (sA < nsh), vB = (sB < nsh), vC = (sC < nsh), vD = (sD < nsh);

    float acc[C2];
    #pragma unroll
    for (int co = 0; co < C2; ++co) acc[co] = c2b[co];

    // ---- chunk loop: conv1+gelu -> LDS, then conv2 accumulate (h1 never in HBM) ----
    #pragma unroll 1
    for (int c0 = 0; c0 < C1; c0 += FCH) {
        __syncthreads();                 // prev chunk fully consumed (and staging ready)
        H1SLOT(sA, bA, vA)
        H1SLOT(sB, bB, vB)
        H1SLOT(sC, bC, vC)
        H1SLOT(sD, bD, vD)
        __syncthreads();                 // h1 chunk visible
        if (is_act) CONV2(c0)
    }

    // ---- passive/frozen pass-through ----
    float* outn = out_fx + n * 4096;
    for (int idx = tid; idx < R * 64; idx += 256) {
        int lr = idx >> 6, c = idx & 63;
        int gi = r0 + lr;
        int pat = (gi + 2 * c) % 3;
        float xv = xn[gi * 64 + c];
        if (pat != 0) outn[gi * 64 + c] = xv;
    }

    // ---- spline at the active site (exact math, proven) ----
    float lj_val = 0.0f;
    if (is_act) {
        int gi = r0 + rr;
        float xv = xn[gi * 64 + cc];

        float kx[NB + 1], ky[NB + 1], sar[NB + 1];
        {
            float m = acc[0];
            #pragma unroll
            for (int qi = 1; qi < NB; ++qi) m = fmaxf(m, acc[qi]);
            float e[NB], ssum = 0.0f;
            #pragma unroll
            for (int qi = 0; qi < NB; ++qi) { e[qi] = expf(acc[qi] - m); ssum += e[qi]; }
            float inv = TWO_PI_F / ssum;
            float run = 0.0f;
            kx[0] = 0.0f;
            #pragma unroll
            for (int qi = 0; qi < NB; ++qi) { run += e[qi]; kx[qi + 1] = run * inv; }
        }
        {
            float m = acc[NB];
            #pragma unroll
            for (int qi = 1; qi < NB; ++qi) m = fmaxf(m, acc[NB + qi]);
            float e[NB], ssum = 0.0f;
            #pragma unroll
            for (int qi = 0; qi < NB; ++qi) { e[qi] = expf(acc[NB + qi] - m); ssum += e[qi]; }
            float inv = TWO_PI_F / ssum;
            float run = 0.0f;
            ky[0] = 0.0f;
            #pragma unroll
            for (int qi = 0; qi < NB; ++qi) { run += e[qi]; ky[qi + 1] = run * inv; }
        }
        #pragma unroll
        for (int qi = 0; qi < NB; ++qi) sar[qi] = softplus_f(acc[2 * NB + qi]);
        sar[NB] = sar[0];
        float t_out = acc[3 * NB];

        float x1 = pos_mod_2pi(xv);
        int k = 0;
        #pragma unroll
        for (int qi = 1; qi <= NB - 1; ++qi) k += (x1 >= kx[qi]) ? 1 : 0;

        float kxk = 0.f, kxk1 = 0.f, kyk = 0.f, kyk1 = 0.f, sk = 0.f, sk1 = 0.f;
        #pragma unroll
        for (int qi = 0; qi <= NB; ++qi) {
            if (qi == k)     { kxk = kx[qi];  kyk = ky[qi];  sk  = sar[qi]; }
            if (qi == k + 1) { kxk1 = kx[qi]; kyk1 = ky[qi]; sk1 = sar[qi]; }
        }

        float wk = kxk1 - kxk;
        float hk = kyk1 - kyk;
        float slope = hk / wk;
        float xi = (x1 - kxk) / wk;
        xi = fminf(fmaxf(xi, 0.0f), 1.0f);
        float om = 1.0f - xi;
        float den = slope + (sk1 + sk - 2.0f * slope) * xi * om;
        float y = kyk + hk * (slope * xi * xi + sk * xi * om) / den;
        float num = slope * slope * (sk1 * xi * xi + 2.0f * slope * xi * om + sk * om * om);
        lj_val = logf(num) - 2.0f * logf(den);

        outn[gi * 64 + cc] = pos_mod_2pi(y + t_out);
    }

    // ---- logJ: wave shuffle -> LDS -> one atomic per block ----
    float r = lj_val;
    #pragma unroll
    for (int off = 32; off > 0; off >>= 1) r += __shfl_down(r, off, 64);
    int lane = tid & 63, wv = tid >> 6;
    if (lane == 0) s_red[wv] = r;
    __syncthreads();
    if (tid == 0)
        atomicAdd(&out_logJ[n], s_red[0] + s_red[1] + s_red[2] + s_red[3]);
}

extern "C" void kernel_launch(void* const* d_in, const int* in_sizes, int n_in,
                              void* d_out, int out_size, void* d_ws, size_t ws_size,
                              hipStream_t stream) {
    const float* x   = (const float*)d_in[0];
    // d_in[1..3] masks: recomputed analytically ((i+2j)%3) -> exact
    const float* c1w = (const float*)d_in[4];
    const float* c1b = (const float*)d_in[5];
    const float* c2w = (const float*)d_in[6];
    const float* c2b = (const float*)d_in[7];

    float* out_fx   = (float*)d_out;
    float* out_logJ = out_fx + (size_t)Nn * Ld * Ld;

    hipMemsetAsync(out_logJ, 0, Nn * sizeof(float), stream);

    dim3 grid(6, Nn);
    csplaq_fused_kernel<<<grid, 256, 0, stream>>>(x, c1w, c1b, c2w, c2b,
                                                  out_fx, out_logJ);
}